// Round 6
// baseline (609.701 us; speedup 1.0000x reference)
//
#include <hip/hip_runtime.h>

#define WW 12
#define CH 32    // CIN == CMID == COUT == 32
#define KERN 3
#define SCAN_T 1024

typedef __attribute__((ext_vector_type(8))) short short8v;
typedef __attribute__((ext_vector_type(4))) short short4v;
typedef __attribute__((ext_vector_type(4))) float f32x4;

__device__ __forceinline__ unsigned short bf16rne(float v) {
  unsigned int u = __float_as_uint(v);
  return (unsigned short)((u + 0x7FFFu + ((u >> 16) & 1u)) >> 16);
}
__device__ __forceinline__ float bf16tofs(short b) {
  return __uint_as_float(((unsigned int)(unsigned short)b) << 16);
}

// ---------------------------------------------------------------------------
// K1: deg[dst] += Ew  and  cnt[dst] += 1
__global__ void degcnt_kernel(const int* __restrict__ dst, const float* __restrict__ Ew,
                              float* __restrict__ deg, int* __restrict__ cnt, int E) {
  int e = blockIdx.x * blockDim.x + threadIdx.x;
  if (e < E) {
    int d = dst[e];
    atomicAdd(&deg[d], Ew[e]);
    atomicAdd(&cnt[d], 1);
  }
}

// K2: single-block chunked exclusive scan of cnt -> rowptr[0..N], wptr copy.
__global__ void scan_kernel(const int* __restrict__ cnt, int* __restrict__ rowptr,
                            int* __restrict__ wptr, int N) {
  __shared__ int sums[SCAN_T];
  const int tid = threadIdx.x;
  const int chunk = (N + SCAN_T - 1) / SCAN_T;
  const int lo = tid * chunk;
  const int hi = min(lo + chunk, N);

  int s = 0;
  for (int i = lo; i < hi; ++i) s += cnt[i];
  sums[tid] = s;
  __syncthreads();
  for (int ofs = 1; ofs < SCAN_T; ofs <<= 1) {
    int t = (tid >= ofs) ? sums[tid - ofs] : 0;
    __syncthreads();
    sums[tid] += t;
    __syncthreads();
  }
  int run = sums[tid] - s;  // exclusive prefix of this chunk
  for (int i = lo; i < hi; ++i) {
    rowptr[i] = run;
    wptr[i] = run;
    run += cnt[i];
  }
  if (tid == SCAN_T - 1) rowptr[N] = sums[SCAN_T - 1];
}

// K3: scatter edges into CSR slots as (src, w_hat) int2 pairs; rsqrt inline
__global__ void fill_kernel(const int* __restrict__ src, const int* __restrict__ dst,
                            const float* __restrict__ Ew, const float* __restrict__ deg,
                            int* __restrict__ wptr, int2* __restrict__ epair, int E) {
  int e = blockIdx.x * blockDim.x + threadIdx.x;
  if (e < E) {
    int s = src[e], d = dst[e];
    float ds = deg[s], dd = deg[d];
    float is = (ds > 0.f) ? rsqrtf(fmaxf(ds, 1e-12f)) : 0.f;
    float id_ = (dd > 0.f) ? rsqrtf(fmaxf(dd, 1e-12f)) : 0.f;
    float wh = -is * Ew[e] * id_;
    int pos = atomicAdd(&wptr[d], 1);
    epair[pos] = make_int2(s, __float_as_int(wh));
  }
}

// K4: pack x (w,n,c) fp32 -> xt (n, w*32+c) bf16.  2-D grid: y = w.
__global__ void pack_kernel(const float* __restrict__ x, unsigned short* __restrict__ xt,
                            int N) {
  int id = blockIdx.x * blockDim.x + threadIdx.x;   // over N*CH
  if (id >= N * CH) return;
  int w = blockIdx.y;
  int n = id >> 5;
  int c = id & 31;
  xt[(size_t)n * (WW * CH) + w * CH + c] = bf16rne(x[(size_t)w * N * CH + id]);
}

// K5: fused weights + fused bias.
//  ffrag[(((w*3+k)*2+m)*2+h)*512 + lane*8 + j]
//      = bf16( sum_d Wcheb[w][m][c][d] * Wconv[o][d][k] ),  c=(l>>4)*8+j, o=(l&15)+16h
//  bfuse[t*32+o] = bconv[o] + sum_{k: 0<=t+k-1<12} sum_d bcheb[t+k-1][d]*Wconv[o][d][k]
__global__ void wpack_kernel(const float* __restrict__ Wcheb, const float* __restrict__ Wconv,
                             const float* __restrict__ bcheb, const float* __restrict__ bconv,
                             unsigned short* __restrict__ ffrag, float* __restrict__ bfuse) {
  int id = blockIdx.x * blockDim.x + threadIdx.x;
  const int NF = 12 * 3 * 2 * 2 * 512;   // 73728
  if (id < NF) {
    int j = id & 7, lane = (id >> 3) & 63, h = (id >> 9) & 1, m = (id >> 10) & 1;
    int rest = id >> 11;
    int k = rest % 3, w = rest / 3;
    int c = ((lane >> 4) << 3) + j;
    int o = (lane & 15) + (h << 4);
    const float* wrow = Wcheb + ((size_t)(w * 2 + m) * 32 + c) * 32;  // over d
    float acc = 0.f;
#pragma unroll
    for (int d = 0; d < 32; ++d) acc += wrow[d] * Wconv[((size_t)o * 32 + d) * 3 + k];
    ffrag[id] = bf16rne(acc);
  } else if (id < NF + 12 * 32) {
    int i2 = id - NF;
    int t = i2 >> 5, o = i2 & 31;
    float acc = bconv[o];
#pragma unroll
    for (int k = 0; k < 3; ++k) {
      int w = t + k - 1;
      if (w < 0 || w >= WW) continue;
      float a = 0.f;
#pragma unroll
      for (int d = 0; d < 32; ++d) a += bcheb[w * 32 + d] * Wconv[((size_t)o * 32 + d) * 3 + k];
      acc += a;
    }
    bfuse[i2] = acc;
  }
}

// K6: gather  zt[n,p](bf16) = sum_{e: dst=n} what[e] * xt[src[e], p]
//     ONE NODE PER WAVE: both 32-lane halves cover the same 768B row
//     (lane&31 owns 12 shorts); halves split the edge list (i0+half, step 2).
__global__ __launch_bounds__(256) void gather_kernel(
    const int* __restrict__ rowptr, const int2* __restrict__ epair,
    const unsigned short* __restrict__ xt, unsigned short* __restrict__ zt, int N) {
  int gt = blockIdx.x * blockDim.x + threadIdx.x;
  int n = gt >> 6;
  if (n >= N) return;
  int lane = gt & 63;
  int half = lane >> 5;
  int l = lane & 31;

  float acc[WW];
#pragma unroll
  for (int j = 0; j < WW; ++j) acc[j] = 0.f;

  int i = rowptr[n] + half;
  const int i1 = rowptr[n + 1];
  // 2 edges per half per iteration (4 edges per wave-iter)
  for (; i + 2 < i1; i += 4) {
    int2 e0 = epair[i];
    int2 e1 = epair[i + 2];
    const unsigned short* p0 = xt + (size_t)e0.x * (WW * CH) + l * WW;
    const unsigned short* p1 = xt + (size_t)e1.x * (WW * CH) + l * WW;
    short4v a0 = *(const short4v*)(p0);
    short4v a1 = *(const short4v*)(p0 + 4);
    short4v a2 = *(const short4v*)(p0 + 8);
    short4v b0 = *(const short4v*)(p1);
    short4v b1 = *(const short4v*)(p1 + 4);
    short4v b2 = *(const short4v*)(p1 + 8);
    float w0 = __int_as_float(e0.y);
    float w1 = __int_as_float(e1.y);
#pragma unroll
    for (int j = 0; j < 4; ++j) {
      acc[j]     = fmaf(w0, bf16tofs(a0[j]), acc[j]);
      acc[4 + j] = fmaf(w0, bf16tofs(a1[j]), acc[4 + j]);
      acc[8 + j] = fmaf(w0, bf16tofs(a2[j]), acc[8 + j]);
      acc[j]     = fmaf(w1, bf16tofs(b0[j]), acc[j]);
      acc[4 + j] = fmaf(w1, bf16tofs(b1[j]), acc[4 + j]);
      acc[8 + j] = fmaf(w1, bf16tofs(b2[j]), acc[8 + j]);
    }
  }
  if (i < i1) {
    int2 e0 = epair[i];
    const unsigned short* p0 = xt + (size_t)e0.x * (WW * CH) + l * WW;
    short4v a0 = *(const short4v*)(p0);
    short4v a1 = *(const short4v*)(p0 + 4);
    short4v a2 = *(const short4v*)(p0 + 8);
    float w0 = __int_as_float(e0.y);
#pragma unroll
    for (int j = 0; j < 4; ++j) {
      acc[j]     = fmaf(w0, bf16tofs(a0[j]), acc[j]);
      acc[4 + j] = fmaf(w0, bf16tofs(a1[j]), acc[4 + j]);
      acc[8 + j] = fmaf(w0, bf16tofs(a2[j]), acc[8 + j]);
    }
  }
  // combine the two halves
#pragma unroll
  for (int j = 0; j < WW; ++j) acc[j] += __shfl_xor(acc[j], 32);

  if (half == 0) {
    unsigned short* q = zt + (size_t)n * (WW * CH) + l * WW;
    short4v o0, o1, o2;
#pragma unroll
    for (int j = 0; j < 4; ++j) {
      o0[j] = (short)bf16rne(acc[j]);
      o1[j] = (short)bf16rne(acc[4 + j]);
      o2[j] = (short)bf16rne(acc[8 + j]);
    }
    *(short4v*)(q) = o0;
    *(short4v*)(q + 4) = o1;
    *(short4v*)(q + 8) = o2;
  }
}

// K7: direct fused mix+conv (no LDS, no H):
//  OUT[n,t,o] = leaky( bfuse[t,o] + sum_{k,w=t+k-1 in range} X[w]@F0[w][k] + Z[w]@F1[w][k] )
//  A-frag: lane holds row=(l&15), k-elems (l>>4)*8+j.  D: node=(l>>4)*4+r, col=(l&15)+16h.
__global__ __launch_bounds__(256) void mc_kernel(
    const unsigned short* __restrict__ xt, const unsigned short* __restrict__ zt,
    const unsigned short* __restrict__ ffrag, const float* __restrict__ bfuse,
    float* __restrict__ out, int N) {
  const int wid = threadIdx.x >> 6;
  const int lane = threadIdx.x & 63;
  const int n0 = (blockIdx.x * 4 + wid) * 16;
  if (n0 >= N) return;
  const int kg = lane >> 4;
  const int arow = lane & 15;
  const int rrow = min(n0 + arow, N - 1);
  const size_t rowbase = (size_t)rrow * (WW * CH) + kg * 8;

  for (int t = 0; t < WW; ++t) {
    f32x4 a0 = {0.f, 0.f, 0.f, 0.f};
    f32x4 a1 = {0.f, 0.f, 0.f, 0.f};
#pragma unroll
    for (int k = 0; k < 3; ++k) {
      int w = t + k - 1;
      if (w < 0 || w >= WW) continue;
      short8v xf = *(const short8v*)(xt + rowbase + w * CH);
      short8v zf = *(const short8v*)(zt + rowbase + w * CH);
      const unsigned short* fb = ffrag + ((size_t)(w * 3 + k) << 11) + (lane << 3);
      short8v f00 = *(const short8v*)(fb);           // m=0,h=0
      short8v f01 = *(const short8v*)(fb + 512);     // m=0,h=1
      short8v f10 = *(const short8v*)(fb + 1024);    // m=1,h=0
      short8v f11 = *(const short8v*)(fb + 1536);    // m=1,h=1
      a0 = __builtin_amdgcn_mfma_f32_16x16x32_bf16(xf, f00, a0, 0, 0, 0);
      a1 = __builtin_amdgcn_mfma_f32_16x16x32_bf16(xf, f01, a1, 0, 0, 0);
      a0 = __builtin_amdgcn_mfma_f32_16x16x32_bf16(zf, f10, a0, 0, 0, 0);
      a1 = __builtin_amdgcn_mfma_f32_16x16x32_bf16(zf, f11, a1, 0, 0, 0);
    }
    const float bf0 = bfuse[t * CH + arow];
    const float bf1 = bfuse[t * CH + arow + 16];
#pragma unroll
    for (int r = 0; r < 4; ++r) {
      int node = n0 + kg * 4 + r;
      if (node >= N) continue;
      float v0 = a0[r] + bf0;
      float v1 = a1[r] + bf1;
      v0 = (v0 >= 0.f) ? v0 : 0.01f * v0;
      v1 = (v1 >= 0.f) ? v1 : 0.01f * v1;
      size_t o = ((size_t)node * WW + t) * CH;
      out[o + arow] = v0;
      out[o + arow + 16] = v1;
    }
  }
}

// ---------------------------------------------------------------------------
extern "C" void kernel_launch(void* const* d_in, const int* in_sizes, int n_in,
                              void* d_out, int out_size, void* d_ws, size_t ws_size,
                              hipStream_t stream) {
  const float* x     = (const float*)d_in[0];
  const int*   A     = (const int*)d_in[1];
  const float* Ew    = (const float*)d_in[2];
  const float* Wcheb = (const float*)d_in[3];
  const float* bcheb = (const float*)d_in[4];
  const float* Wconv = (const float*)d_in[5];
  const float* bconv = (const float*)d_in[6];
  float* out = (float*)d_out;

  const int E = in_sizes[2];
  const int N = in_sizes[0] / (WW * CH);
  const int* srcA = A;
  const int* dstA = A + E;

  char* ws = (char*)d_ws;
  size_t off = 0;
  auto alloc = [&](size_t bytes) -> void* {
    void* p = ws + off;
    off += (bytes + 255) / 256 * 256;
    return p;
  };
  float* deg    = (float*)alloc((size_t)N * 4);
  int*   cnt    = (int*)alloc((size_t)N * 4);
  int*   rowptr = (int*)alloc((size_t)(N + 1) * 4);
  int*   wptr   = (int*)alloc((size_t)N * 4);
  int2*  epair  = (int2*)alloc((size_t)E * 8);
  unsigned short* xt    = (unsigned short*)alloc((size_t)N * WW * CH * 2);
  unsigned short* zt    = (unsigned short*)alloc((size_t)N * WW * CH * 2);
  unsigned short* ffrag = (unsigned short*)alloc((size_t)73728 * 2);
  float* bfuse = (float*)alloc((size_t)12 * 32 * 4);
  (void)ws_size;

  // deg and cnt are adjacent: one memset covers both
  hipMemsetAsync(deg, 0, (size_t)((char*)(cnt + N) - (char*)deg), stream);

  degcnt_kernel<<<(E + 255) / 256, 256, 0, stream>>>(dstA, Ew, deg, cnt, E);
  scan_kernel<<<1, SCAN_T, 0, stream>>>(cnt, rowptr, wptr, N);
  fill_kernel<<<(E + 255) / 256, 256, 0, stream>>>(srcA, dstA, Ew, deg, wptr, epair, E);

  dim3 gpack((N * CH + 255) / 256, WW);
  pack_kernel<<<gpack, 256, 0, stream>>>(x, xt, N);
  wpack_kernel<<<(73728 + 384 + 255) / 256, 256, 0, stream>>>(Wcheb, Wconv, bcheb, bconv, ffrag, bfuse);

  long long gtot = (long long)N * 64;
  gather_kernel<<<(unsigned)((gtot + 255) / 256), 256, 0, stream>>>(rowptr, epair, xt, zt, N);

  int ntiles = (N + 15) / 16;            // 16-node wave tiles
  int mcblocks = (ntiles + 3) / 4;       // 4 waves per block
  mc_kernel<<<mcblocks, 256, 0, stream>>>(xt, zt, ffrag, bfuse, out, N);
}

// Round 7
// 476.613 us; speedup vs baseline: 1.2792x; 1.2792x over previous
//
#include <hip/hip_runtime.h>

#define WW 12
#define CH 32    // CIN == CMID == COUT == 32
#define KERN 3
#define SCAN_T 1024
#define ROWB 384   // bytes per fp8 row = WW*CH; elements per bf16 row

typedef __attribute__((ext_vector_type(8))) short short8v;
typedef __attribute__((ext_vector_type(4))) short short4v;
typedef __attribute__((ext_vector_type(4))) float f32x4;

__device__ __forceinline__ unsigned short bf16rne(float v) {
  unsigned int u = __float_as_uint(v);
  return (unsigned short)((u + 0x7FFFu + ((u >> 16) & 1u)) >> 16);
}

// exact-RNE f32 -> fp8 e4m3 (OCP, saturating, no NaN production)
__device__ __forceinline__ unsigned char fp8e4m3(float x) {
  unsigned int u = __float_as_uint(x);
  unsigned int s = (u >> 24) & 0x80u;
  float ax = fabsf(x);
  if (ax >= 464.f) return (unsigned char)(s | 0x7E);       // 448
  if (ax < 0.015625f) {                                    // subnormal: m = RNE(ax*512)
    int m = __float2int_rn(ax * 512.f);
    return (unsigned char)(s | (unsigned)m);               // m==8 carries to e=1,m=0
  }
  unsigned int au = u & 0x7fffffffu;
  au += 0x7FFFFu + ((au >> 20) & 1u);                      // RNE on 20 dropped bits
  int e = (int)(au >> 23) - 127 + 7;
  unsigned int m = (au >> 20) & 7u;
  if (e > 15 || (e == 15 && m == 7)) return (unsigned char)(s | 0x7E);
  return (unsigned char)(s | ((unsigned)e << 3) | m);
}

// decode 4 fp8 from one dword, fused multiply-accumulate into acc[0..3]
__device__ __forceinline__ void dec4fma(unsigned int u, float wh, float* acc) {
#if __has_builtin(__builtin_amdgcn_cvt_pk_f32_fp8)
  auto lo = __builtin_amdgcn_cvt_pk_f32_fp8((int)u, false);  // bytes 0,1
  auto hi = __builtin_amdgcn_cvt_pk_f32_fp8((int)u, true);   // bytes 2,3
  acc[0] = fmaf(wh, lo[0], acc[0]);
  acc[1] = fmaf(wh, lo[1], acc[1]);
  acc[2] = fmaf(wh, hi[0], acc[2]);
  acc[3] = fmaf(wh, hi[1], acc[3]);
#else
#pragma unroll
  for (int j = 0; j < 4; ++j) {
    unsigned int b = (u >> (8 * j)) & 0xffu;
    float f = __uint_as_float(((b & 0x80u) << 24) | ((b & 0x7fu) << 20)) * 0x1.0p120f;
    acc[j] = fmaf(wh, f, acc[j]);
  }
#endif
}

// ---------------------------------------------------------------------------
// K1: degcnt[dst] += (1<<32) | round(Ew * 2^25)   (count hi32, fixed-point deg lo32)
__global__ void degcnt_kernel(const int* __restrict__ dst, const float* __restrict__ Ew,
                              unsigned long long* __restrict__ degcnt, int E) {
  int e = blockIdx.x * blockDim.x + threadIdx.x;
  if (e < E) {
    unsigned int q = (unsigned int)__float2int_rn(Ew[e] * 33554432.f);
    atomicAdd(&degcnt[dst[e]], (1ULL << 32) | (unsigned long long)q);
  }
}

// K2: single-block chunked exclusive scan of counts -> rowptr[0..N], wptr copy.
__global__ void scan_kernel(const unsigned long long* __restrict__ degcnt,
                            int* __restrict__ rowptr, int* __restrict__ wptr, int N) {
  __shared__ int sums[SCAN_T];
  const int tid = threadIdx.x;
  const int chunk = (N + SCAN_T - 1) / SCAN_T;
  const int lo = tid * chunk;
  const int hi = min(lo + chunk, N);

  int s = 0;
  for (int i = lo; i < hi; ++i) s += (int)(degcnt[i] >> 32);
  sums[tid] = s;
  __syncthreads();
  for (int ofs = 1; ofs < SCAN_T; ofs <<= 1) {
    int t = (tid >= ofs) ? sums[tid - ofs] : 0;
    __syncthreads();
    sums[tid] += t;
    __syncthreads();
  }
  int run = sums[tid] - s;
  for (int i = lo; i < hi; ++i) {
    rowptr[i] = run;
    wptr[i] = run;
    run += (int)(degcnt[i] >> 32);
  }
  if (tid == SCAN_T - 1) rowptr[N] = sums[SCAN_T - 1];
}

// K3: scatter edges into CSR slots as (src, w_hat) int2 pairs; dinv from fixed-point deg
__global__ void fill_kernel(const int* __restrict__ src, const int* __restrict__ dst,
                            const float* __restrict__ Ew,
                            const unsigned long long* __restrict__ degcnt,
                            int* __restrict__ wptr, int2* __restrict__ epair, int E) {
  int e = blockIdx.x * blockDim.x + threadIdx.x;
  if (e < E) {
    int s = src[e], d = dst[e];
    float ds = (float)(unsigned int)degcnt[s] * (1.f / 33554432.f);
    float dd = (float)(unsigned int)degcnt[d] * (1.f / 33554432.f);
    float is = (ds > 0.f) ? rsqrtf(fmaxf(ds, 1e-12f)) : 0.f;
    float id_ = (dd > 0.f) ? rsqrtf(fmaxf(dd, 1e-12f)) : 0.f;
    float wh = -is * Ew[e] * id_;
    int pos = atomicAdd(&wptr[d], 1);
    epair[pos] = make_int2(s, __float_as_int(wh));
  }
}

// K4: pack x (w,n,c) fp32 -> xt (n, w*32+c) bf16  AND  xq (n, w*32+c) fp8.
//     blockIdx.y == w.  blockIdx.y==0 low ids also pack MFMA weight fragments.
__global__ void pack_kernel(const float* __restrict__ x, const float* __restrict__ Wcheb,
                            const float* __restrict__ Wconv,
                            unsigned short* __restrict__ xt, unsigned char* __restrict__ xq,
                            unsigned short* __restrict__ wb01, unsigned short* __restrict__ wbc,
                            int N) {
  int id = blockIdx.x * blockDim.x + threadIdx.x;   // over N*CH
  int w = blockIdx.y;
  if (id < N * CH) {
    int n = id >> 5;
    int c = id & 31;
    float v = x[(size_t)w * N * CH + id];
    xt[(size_t)n * ROWB + w * CH + c] = bf16rne(v);
    xq[(size_t)n * ROWB + w * CH + c] = fp8e4m3(v);
  }
  if (w == 0) {
    if (id < 12 * 2 * 2 * 64 * 8) {
      int j = id & 7, l = (id >> 3) & 63, h = (id >> 9) & 1, m = (id >> 10) & 1, ww = id >> 11;
      int k = ((l >> 4) << 3) + j;
      int d = (l & 15) + (h << 4);
      wb01[id] = bf16rne(Wcheb[((size_t)(ww * 2 + m) * 32 + k) * 32 + d]);
    } else if (id < 24576 + 3 * 2 * 64 * 8) {
      int i2 = id - 24576;
      int j = i2 & 7, l = (i2 >> 3) & 63, h = (i2 >> 9) & 1, k = i2 >> 10;
      int c = ((l >> 4) << 3) + j;
      int o = (l & 15) + (h << 4);
      wbc[i2] = bf16rne(Wconv[((size_t)(o * 32 + c)) * 3 + k]);
    }
  }
}

// K5: gather  zt[n,p](bf16) = sum_{e: dst=n} what[e] * fp8(x)[src[e], p]
//     one node per wave; lane l&31 owns bytes [12l,12l+12) of the 384B row;
//     halves split the edge list, combined by shfl_xor(32).
__global__ __launch_bounds__(256) void gather_kernel(
    const int* __restrict__ rowptr, const int2* __restrict__ epair,
    const unsigned char* __restrict__ xq, unsigned short* __restrict__ zt, int N) {
  int gt = blockIdx.x * blockDim.x + threadIdx.x;
  int n = gt >> 6;
  if (n >= N) return;
  int lane = gt & 63;
  int half = lane >> 5;
  int l = lane & 31;

  float acc[WW];
#pragma unroll
  for (int j = 0; j < WW; ++j) acc[j] = 0.f;

  int i = rowptr[n] + half;
  const int i1 = rowptr[n + 1];
  for (; i + 2 < i1; i += 4) {        // 2 edges per half per iteration
    int2 e0 = epair[i];
    int2 e1 = epair[i + 2];
    const unsigned int* p0 = (const unsigned int*)(xq + (size_t)e0.x * ROWB + l * 12);
    const unsigned int* p1 = (const unsigned int*)(xq + (size_t)e1.x * ROWB + l * 12);
    unsigned int a0 = p0[0], a1 = p0[1], a2 = p0[2];
    unsigned int b0 = p1[0], b1 = p1[1], b2 = p1[2];
    float w0 = __int_as_float(e0.y);
    float w1 = __int_as_float(e1.y);
    dec4fma(a0, w0, acc + 0);
    dec4fma(a1, w0, acc + 4);
    dec4fma(a2, w0, acc + 8);
    dec4fma(b0, w1, acc + 0);
    dec4fma(b1, w1, acc + 4);
    dec4fma(b2, w1, acc + 8);
  }
  if (i < i1) {
    int2 e0 = epair[i];
    const unsigned int* p0 = (const unsigned int*)(xq + (size_t)e0.x * ROWB + l * 12);
    unsigned int a0 = p0[0], a1 = p0[1], a2 = p0[2];
    float w0 = __int_as_float(e0.y);
    dec4fma(a0, w0, acc + 0);
    dec4fma(a1, w0, acc + 4);
    dec4fma(a2, w0, acc + 8);
  }
#pragma unroll
  for (int j = 0; j < WW; ++j) acc[j] += __shfl_xor(acc[j], 32);

  if (half == 0) {
    unsigned short* q = zt + (size_t)n * ROWB + l * 12;
    short4v o0, o1, o2;
#pragma unroll
    for (int j = 0; j < 4; ++j) {
      o0[j] = (short)bf16rne(acc[j]);
      o1[j] = (short)bf16rne(acc[4 + j]);
      o2[j] = (short)bf16rne(acc[8 + j]);
    }
    *(short4v*)(q) = o0;
    *(short4v*)(q + 4) = o1;
    *(short4v*)(q + 8) = o2;
  }
}

// K6 (fused mix+conv, MFMA, rolling LDS ring): per wave, 16 nodes.
//  computeH(w): H[w] = bcheb[w] + X[w]@W0[w] + Z[w]@W1[w]  -> LDS ring slot w&3
//  convT(t):    OUT[t] = leaky( sum_k H[t+k-1] @ Wc[k] + bconv )
__global__ __launch_bounds__(256) void mc_kernel(
    const unsigned short* __restrict__ xt, const unsigned short* __restrict__ zt,
    const unsigned short* __restrict__ wb01, const unsigned short* __restrict__ wbc,
    const float* __restrict__ bcheb, const float* __restrict__ bconv,
    float* __restrict__ out, int N) {
  __shared__ __align__(16) unsigned short hts[4][4][16][40];  // [wave][ring][row][40-pad]
  const int wid = threadIdx.x >> 6;
  const int lane = threadIdx.x & 63;
  const int n0 = (blockIdx.x * 4 + wid) * 16;
  if (n0 >= N) return;
  const int kg = lane >> 4;
  const int arow = lane & 15;
  const int rrow = min(n0 + arow, N - 1);   // clamp tail reads

  short8v wcf0[3], wcf1[3];
#pragma unroll
  for (int k = 0; k < 3; ++k) {
    wcf0[k] = *(const short8v*)(wbc + (((k * 2 + 0) * 64 + lane) << 3));
    wcf1[k] = *(const short8v*)(wbc + (((k * 2 + 1) * 64 + lane) << 3));
  }
  const float bc0 = bconv[arow];
  const float bc1 = bconv[arow + 16];

  auto computeH = [&](int w) {
    const size_t fofs = (size_t)rrow * ROWB + w * CH + kg * 8;
    short8v xf = *(const short8v*)(xt + fofs);
    short8v zf = *(const short8v*)(zt + fofs);
    unsigned short* hrow = &hts[wid][w & 3][0][0];
#pragma unroll
    for (int h = 0; h < 2; ++h) {
      short8v w0f = *(const short8v*)(wb01 + ((((w * 2 + 0) * 2 + h) * 64 + lane) << 3));
      short8v w1f = *(const short8v*)(wb01 + ((((w * 2 + 1) * 2 + h) * 64 + lane) << 3));
      f32x4 acc = {0.f, 0.f, 0.f, 0.f};
      acc = __builtin_amdgcn_mfma_f32_16x16x32_bf16(xf, w0f, acc, 0, 0, 0);
      acc = __builtin_amdgcn_mfma_f32_16x16x32_bf16(zf, w1f, acc, 0, 0, 0);
      const int d = arow + (h << 4);
      const float bias = bcheb[w * CH + d];
#pragma unroll
      for (int r = 0; r < 4; ++r) {
        hrow[(kg * 4 + r) * 40 + d] = bf16rne(acc[r] + bias);
      }
    }
  };

  auto convT = [&](int t) {
    f32x4 a0 = {0.f, 0.f, 0.f, 0.f};
    f32x4 a1 = {0.f, 0.f, 0.f, 0.f};
#pragma unroll
    for (int k = 0; k < 3; ++k) {
      int w = t + k - 1;
      if (w < 0 || w >= WW) continue;
      short8v hf = *(const short8v*)(&hts[wid][w & 3][arow][kg * 8]);
      a0 = __builtin_amdgcn_mfma_f32_16x16x32_bf16(hf, wcf0[k], a0, 0, 0, 0);
      a1 = __builtin_amdgcn_mfma_f32_16x16x32_bf16(hf, wcf1[k], a1, 0, 0, 0);
    }
#pragma unroll
    for (int r = 0; r < 4; ++r) {
      int node = n0 + kg * 4 + r;
      if (node >= N) continue;               // guard tail writes
      float v0 = a0[r] + bc0;
      float v1 = a1[r] + bc1;
      v0 = (v0 >= 0.f) ? v0 : 0.01f * v0;
      v1 = (v1 >= 0.f) ? v1 : 0.01f * v1;
      size_t o = ((size_t)node * WW + t) * CH;
      out[o + arow] = v0;
      out[o + arow + 16] = v1;
    }
  };

  computeH(0);
  computeH(1);
  convT(0);
  for (int w = 2; w < WW; ++w) {
    computeH(w);
    convT(w - 1);
  }
  convT(WW - 1);
}

// ---------------------------------------------------------------------------
extern "C" void kernel_launch(void* const* d_in, const int* in_sizes, int n_in,
                              void* d_out, int out_size, void* d_ws, size_t ws_size,
                              hipStream_t stream) {
  const float* x     = (const float*)d_in[0];
  const int*   A     = (const int*)d_in[1];
  const float* Ew    = (const float*)d_in[2];
  const float* Wcheb = (const float*)d_in[3];
  const float* bcheb = (const float*)d_in[4];
  const float* Wconv = (const float*)d_in[5];
  const float* bconv = (const float*)d_in[6];
  float* out = (float*)d_out;

  const int E = in_sizes[2];
  const int N = in_sizes[0] / (WW * CH);
  const int* srcA = A;
  const int* dstA = A + E;

  char* ws = (char*)d_ws;
  size_t off = 0;
  auto alloc = [&](size_t bytes) -> void* {
    void* p = ws + off;
    off += (bytes + 255) / 256 * 256;
    return p;
  };
  unsigned long long* degcnt = (unsigned long long*)alloc((size_t)N * 8);
  int*   rowptr = (int*)alloc((size_t)(N + 1) * 4);
  int*   wptr   = (int*)alloc((size_t)N * 4);
  int2*  epair  = (int2*)alloc((size_t)E * 8);
  unsigned short* xt   = (unsigned short*)alloc((size_t)N * ROWB * 2);
  unsigned char*  xq   = (unsigned char*)alloc((size_t)N * ROWB);
  unsigned short* zt   = (unsigned short*)alloc((size_t)N * ROWB * 2);
  unsigned short* wb01 = (unsigned short*)alloc((size_t)24576 * 2);
  unsigned short* wbc  = (unsigned short*)alloc((size_t)3072 * 2);
  (void)ws_size;

  hipMemsetAsync(degcnt, 0, (size_t)N * 8, stream);

  degcnt_kernel<<<(E + 255) / 256, 256, 0, stream>>>(dstA, Ew, degcnt, E);
  scan_kernel<<<1, SCAN_T, 0, stream>>>(degcnt, rowptr, wptr, N);
  fill_kernel<<<(E + 255) / 256, 256, 0, stream>>>(srcA, dstA, Ew, degcnt, wptr, epair, E);

  dim3 gpack((N * CH + 255) / 256, WW);
  pack_kernel<<<gpack, 256, 0, stream>>>(x, Wcheb, Wconv, xt, xq, wb01, wbc, N);

  long long gtot = (long long)N * 64;
  gather_kernel<<<(unsigned)((gtot + 255) / 256), 256, 0, stream>>>(rowptr, epair, xq, zt, N);

  int ntiles = (N + 15) / 16;            // 16-node wave tiles
  int mcblocks = (ntiles + 3) / 4;       // 4 waves per block
  mc_kernel<<<mcblocks, 256, 0, stream>>>(xt, zt, wb01, wbc, bcheb, bconv, out, N);
}

// Round 8
// 338.183 us; speedup vs baseline: 1.8029x; 1.4093x over previous
//
#include <hip/hip_runtime.h>

#define WW 12
#define CH 32    // CIN == CMID == COUT == 32
#define KERN 3
#define SBT 256    // scan block size (two-level scan; needs ceil(N/SBT) <= SBT)
#define ROWB 384   // bytes per fp8 row = WW*CH; elements per bf16 row

typedef __attribute__((ext_vector_type(8))) short short8v;
typedef __attribute__((ext_vector_type(4))) short short4v;
typedef __attribute__((ext_vector_type(4))) float f32x4;

__device__ __forceinline__ unsigned short bf16rne(float v) {
  unsigned int u = __float_as_uint(v);
  return (unsigned short)((u + 0x7FFFu + ((u >> 16) & 1u)) >> 16);
}

// exact-RNE f32 -> fp8 e4m3 (OCP, saturating, no NaN production)
__device__ __forceinline__ unsigned char fp8e4m3(float x) {
  unsigned int u = __float_as_uint(x);
  unsigned int s = (u >> 24) & 0x80u;
  float ax = fabsf(x);
  if (ax >= 464.f) return (unsigned char)(s | 0x7E);       // 448
  if (ax < 0.015625f) {                                    // subnormal: m = RNE(ax*512)
    int m = __float2int_rn(ax * 512.f);
    return (unsigned char)(s | (unsigned)m);               // m==8 carries to e=1,m=0
  }
  unsigned int au = u & 0x7fffffffu;
  au += 0x7FFFFu + ((au >> 20) & 1u);                      // RNE on 20 dropped bits
  int e = (int)(au >> 23) - 127 + 7;
  unsigned int m = (au >> 20) & 7u;
  if (e > 15 || (e == 15 && m == 7)) return (unsigned char)(s | 0x7E);
  return (unsigned char)(s | ((unsigned)e << 3) | m);
}

// decode 4 fp8 from one dword, fused multiply-accumulate into acc[0..3]
__device__ __forceinline__ void dec4fma(unsigned int u, float wh, float* acc) {
#if __has_builtin(__builtin_amdgcn_cvt_pk_f32_fp8)
  auto lo = __builtin_amdgcn_cvt_pk_f32_fp8((int)u, false);  // bytes 0,1
  auto hi = __builtin_amdgcn_cvt_pk_f32_fp8((int)u, true);   // bytes 2,3
  acc[0] = fmaf(wh, lo[0], acc[0]);
  acc[1] = fmaf(wh, lo[1], acc[1]);
  acc[2] = fmaf(wh, hi[0], acc[2]);
  acc[3] = fmaf(wh, hi[1], acc[3]);
#else
#pragma unroll
  for (int j = 0; j < 4; ++j) {
    unsigned int b = (u >> (8 * j)) & 0xffu;
    float f = __uint_as_float(((b & 0x80u) << 24) | ((b & 0x7fu) << 20)) * 0x1.0p120f;
    acc[j] = fmaf(wh, f, acc[j]);
  }
#endif
}

// ---------------------------------------------------------------------------
// K1: degcnt[dst] += (1<<32) | round(Ew * 2^25)   (count hi32, fixed-point deg lo32)
__global__ void degcnt_kernel(const int* __restrict__ dst, const float* __restrict__ Ew,
                              unsigned long long* __restrict__ degcnt, int E) {
  int e = blockIdx.x * blockDim.x + threadIdx.x;
  if (e < E) {
    unsigned int q = (unsigned int)__float2int_rn(Ew[e] * 33554432.f);
    atomicAdd(&degcnt[dst[e]], (1ULL << 32) | (unsigned long long)q);
  }
}

// K2a: per-block reduction of counts -> bsum[b]
__global__ void scanA_kernel(const unsigned long long* __restrict__ degcnt,
                             int* __restrict__ bsum, int N) {
  __shared__ int red[SBT];
  int i = blockIdx.x * SBT + threadIdx.x;
  red[threadIdx.x] = (i < N) ? (int)(degcnt[i] >> 32) : 0;
  __syncthreads();
  for (int o = SBT / 2; o > 0; o >>= 1) {
    if (threadIdx.x < o) red[threadIdx.x] += red[threadIdx.x + o];
    __syncthreads();
  }
  if (threadIdx.x == 0) bsum[blockIdx.x] = red[0];
}

// K2b: single-block exclusive scan of bsum (nb <= SBT); writes rowptr[N]=total
__global__ void scanB_kernel(int* __restrict__ bsum, int* __restrict__ rowptr,
                             int nb, int N) {
  __shared__ int tmp[SBT];
  int tid = threadIdx.x;
  int v = (tid < nb) ? bsum[tid] : 0;
  tmp[tid] = v;
  __syncthreads();
  for (int o = 1; o < SBT; o <<= 1) {
    int t = (tid >= o) ? tmp[tid - o] : 0;
    __syncthreads();
    tmp[tid] += t;
    __syncthreads();
  }
  if (tid < nb) bsum[tid] = tmp[tid] - v;        // exclusive block offsets
  if (tid == SBT - 1) rowptr[N] = tmp[SBT - 1];  // grand total
}

// K2c: per-block LDS ladder + block offset -> rowptr/wptr
__global__ void scanC_kernel(const unsigned long long* __restrict__ degcnt,
                             const int* __restrict__ bsum,
                             int* __restrict__ rowptr, int* __restrict__ wptr, int N) {
  __shared__ int tmp[SBT];
  int tid = threadIdx.x;
  int i = blockIdx.x * SBT + tid;
  int v = (i < N) ? (int)(degcnt[i] >> 32) : 0;
  tmp[tid] = v;
  __syncthreads();
  for (int o = 1; o < SBT; o <<= 1) {
    int t = (tid >= o) ? tmp[tid - o] : 0;
    __syncthreads();
    tmp[tid] += t;
    __syncthreads();
  }
  if (i < N) {
    int ex = bsum[blockIdx.x] + tmp[tid] - v;
    rowptr[i] = ex;
    wptr[i] = ex;
  }
}

// K3: scatter edges into CSR slots as (src, w_hat) int2 pairs; dinv from fixed-point deg
__global__ void fill_kernel(const int* __restrict__ src, const int* __restrict__ dst,
                            const float* __restrict__ Ew,
                            const unsigned long long* __restrict__ degcnt,
                            int* __restrict__ wptr, int2* __restrict__ epair, int E) {
  int e = blockIdx.x * blockDim.x + threadIdx.x;
  if (e < E) {
    int s = src[e], d = dst[e];
    float ds = (float)(unsigned int)degcnt[s] * (1.f / 33554432.f);
    float dd = (float)(unsigned int)degcnt[d] * (1.f / 33554432.f);
    float is = (ds > 0.f) ? rsqrtf(fmaxf(ds, 1e-12f)) : 0.f;
    float id_ = (dd > 0.f) ? rsqrtf(fmaxf(dd, 1e-12f)) : 0.f;
    float wh = -is * Ew[e] * id_;
    int pos = atomicAdd(&wptr[d], 1);
    epair[pos] = make_int2(s, __float_as_int(wh));
  }
}

// K4: pack x (w,n,c) fp32 -> xt (n, w*32+c) bf16  AND  xq (n, w*32+c) fp8.
//     blockIdx.y == w.  blockIdx.y==0 low ids also pack MFMA weight fragments.
__global__ void pack_kernel(const float* __restrict__ x, const float* __restrict__ Wcheb,
                            const float* __restrict__ Wconv,
                            unsigned short* __restrict__ xt, unsigned char* __restrict__ xq,
                            unsigned short* __restrict__ wb01, unsigned short* __restrict__ wbc,
                            int N) {
  int id = blockIdx.x * blockDim.x + threadIdx.x;   // over N*CH
  int w = blockIdx.y;
  if (id < N * CH) {
    int n = id >> 5;
    int c = id & 31;
    float v = x[(size_t)w * N * CH + id];
    xt[(size_t)n * ROWB + w * CH + c] = bf16rne(v);
    xq[(size_t)n * ROWB + w * CH + c] = fp8e4m3(v);
  }
  if (w == 0) {
    if (id < 12 * 2 * 2 * 64 * 8) {
      int j = id & 7, l = (id >> 3) & 63, h = (id >> 9) & 1, m = (id >> 10) & 1, ww = id >> 11;
      int k = ((l >> 4) << 3) + j;
      int d = (l & 15) + (h << 4);
      wb01[id] = bf16rne(Wcheb[((size_t)(ww * 2 + m) * 32 + k) * 32 + d]);
    } else if (id < 24576 + 3 * 2 * 64 * 8) {
      int i2 = id - 24576;
      int j = i2 & 7, l = (i2 >> 3) & 63, h = (i2 >> 9) & 1, k = i2 >> 10;
      int c = ((l >> 4) << 3) + j;
      int o = (l & 15) + (h << 4);
      wbc[i2] = bf16rne(Wconv[((size_t)(o * 32 + c)) * 3 + k]);
    }
  }
}

// K5: gather  zt[n,p](bf16) = sum_{e: dst=n} what[e] * fp8(x)[src[e], p]
//     one node per wave; lane l&31 owns bytes [12l,12l+12) of the 384B row;
//     halves split the edge list, combined by shfl_xor(32).
__global__ __launch_bounds__(256) void gather_kernel(
    const int* __restrict__ rowptr, const int2* __restrict__ epair,
    const unsigned char* __restrict__ xq, unsigned short* __restrict__ zt, int N) {
  int gt = blockIdx.x * blockDim.x + threadIdx.x;
  int n = gt >> 6;
  if (n >= N) return;
  int lane = gt & 63;
  int half = lane >> 5;
  int l = lane & 31;

  float acc[WW];
#pragma unroll
  for (int j = 0; j < WW; ++j) acc[j] = 0.f;

  int i = rowptr[n] + half;
  const int i1 = rowptr[n + 1];
  for (; i + 2 < i1; i += 4) {        // 2 edges per half per iteration
    int2 e0 = epair[i];
    int2 e1 = epair[i + 2];
    const unsigned int* p0 = (const unsigned int*)(xq + (size_t)e0.x * ROWB + l * 12);
    const unsigned int* p1 = (const unsigned int*)(xq + (size_t)e1.x * ROWB + l * 12);
    unsigned int a0 = p0[0], a1 = p0[1], a2 = p0[2];
    unsigned int b0 = p1[0], b1 = p1[1], b2 = p1[2];
    float w0 = __int_as_float(e0.y);
    float w1 = __int_as_float(e1.y);
    dec4fma(a0, w0, acc + 0);
    dec4fma(a1, w0, acc + 4);
    dec4fma(a2, w0, acc + 8);
    dec4fma(b0, w1, acc + 0);
    dec4fma(b1, w1, acc + 4);
    dec4fma(b2, w1, acc + 8);
  }
  if (i < i1) {
    int2 e0 = epair[i];
    const unsigned int* p0 = (const unsigned int*)(xq + (size_t)e0.x * ROWB + l * 12);
    unsigned int a0 = p0[0], a1 = p0[1], a2 = p0[2];
    float w0 = __int_as_float(e0.y);
    dec4fma(a0, w0, acc + 0);
    dec4fma(a1, w0, acc + 4);
    dec4fma(a2, w0, acc + 8);
  }
#pragma unroll
  for (int j = 0; j < WW; ++j) acc[j] += __shfl_xor(acc[j], 32);

  if (half == 0) {
    unsigned short* q = zt + (size_t)n * ROWB + l * 12;
    short4v o0, o1, o2;
#pragma unroll
    for (int j = 0; j < 4; ++j) {
      o0[j] = (short)bf16rne(acc[j]);
      o1[j] = (short)bf16rne(acc[4 + j]);
      o2[j] = (short)bf16rne(acc[8 + j]);
    }
    *(short4v*)(q) = o0;
    *(short4v*)(q + 4) = o1;
    *(short4v*)(q + 8) = o2;
  }
}

// K6 (fused mix+conv, MFMA, rolling LDS ring): per wave, 16 nodes.
//  computeH(w): H[w] = bcheb[w] + X[w]@W0[w] + Z[w]@W1[w]  -> LDS ring slot w&3
//  convT(t):    OUT[t] = leaky( sum_k H[t+k-1] @ Wc[k] + bconv )
__global__ __launch_bounds__(256) void mc_kernel(
    const unsigned short* __restrict__ xt, const unsigned short* __restrict__ zt,
    const unsigned short* __restrict__ wb01, const unsigned short* __restrict__ wbc,
    const float* __restrict__ bcheb, const float* __restrict__ bconv,
    float* __restrict__ out, int N) {
  __shared__ __align__(16) unsigned short hts[4][4][16][40];  // [wave][ring][row][40-pad]
  const int wid = threadIdx.x >> 6;
  const int lane = threadIdx.x & 63;
  const int n0 = (blockIdx.x * 4 + wid) * 16;
  if (n0 >= N) return;
  const int kg = lane >> 4;
  const int arow = lane & 15;
  const int rrow = min(n0 + arow, N - 1);   // clamp tail reads

  short8v wcf0[3], wcf1[3];
#pragma unroll
  for (int k = 0; k < 3; ++k) {
    wcf0[k] = *(const short8v*)(wbc + (((k * 2 + 0) * 64 + lane) << 3));
    wcf1[k] = *(const short8v*)(wbc + (((k * 2 + 1) * 64 + lane) << 3));
  }
  const float bc0 = bconv[arow];
  const float bc1 = bconv[arow + 16];

  auto computeH = [&](int w) {
    const size_t fofs = (size_t)rrow * ROWB + w * CH + kg * 8;
    short8v xf = *(const short8v*)(xt + fofs);
    short8v zf = *(const short8v*)(zt + fofs);
    unsigned short* hrow = &hts[wid][w & 3][0][0];
#pragma unroll
    for (int h = 0; h < 2; ++h) {
      short8v w0f = *(const short8v*)(wb01 + ((((w * 2 + 0) * 2 + h) * 64 + lane) << 3));
      short8v w1f = *(const short8v*)(wb01 + ((((w * 2 + 1) * 2 + h) * 64 + lane) << 3));
      f32x4 acc = {0.f, 0.f, 0.f, 0.f};
      acc = __builtin_amdgcn_mfma_f32_16x16x32_bf16(xf, w0f, acc, 0, 0, 0);
      acc = __builtin_amdgcn_mfma_f32_16x16x32_bf16(zf, w1f, acc, 0, 0, 0);
      const int d = arow + (h << 4);
      const float bias = bcheb[w * CH + d];
#pragma unroll
      for (int r = 0; r < 4; ++r) {
        hrow[(kg * 4 + r) * 40 + d] = bf16rne(acc[r] + bias);
      }
    }
  };

  auto convT = [&](int t) {
    f32x4 a0 = {0.f, 0.f, 0.f, 0.f};
    f32x4 a1 = {0.f, 0.f, 0.f, 0.f};
#pragma unroll
    for (int k = 0; k < 3; ++k) {
      int w = t + k - 1;
      if (w < 0 || w >= WW) continue;
      short8v hf = *(const short8v*)(&hts[wid][w & 3][arow][kg * 8]);
      a0 = __builtin_amdgcn_mfma_f32_16x16x32_bf16(hf, wcf0[k], a0, 0, 0, 0);
      a1 = __builtin_amdgcn_mfma_f32_16x16x32_bf16(hf, wcf1[k], a1, 0, 0, 0);
    }
#pragma unroll
    for (int r = 0; r < 4; ++r) {
      int node = n0 + kg * 4 + r;
      if (node >= N) continue;               // guard tail writes
      float v0 = a0[r] + bc0;
      float v1 = a1[r] + bc1;
      v0 = (v0 >= 0.f) ? v0 : 0.01f * v0;
      v1 = (v1 >= 0.f) ? v1 : 0.01f * v1;
      size_t o = ((size_t)node * WW + t) * CH;
      out[o + arow] = v0;
      out[o + arow + 16] = v1;
    }
  };

  computeH(0);
  computeH(1);
  convT(0);
  for (int w = 2; w < WW; ++w) {
    computeH(w);
    convT(w - 1);
  }
  convT(WW - 1);
}

// ---------------------------------------------------------------------------
extern "C" void kernel_launch(void* const* d_in, const int* in_sizes, int n_in,
                              void* d_out, int out_size, void* d_ws, size_t ws_size,
                              hipStream_t stream) {
  const float* x     = (const float*)d_in[0];
  const int*   A     = (const int*)d_in[1];
  const float* Ew    = (const float*)d_in[2];
  const float* Wcheb = (const float*)d_in[3];
  const float* bcheb = (const float*)d_in[4];
  const float* Wconv = (const float*)d_in[5];
  const float* bconv = (const float*)d_in[6];
  float* out = (float*)d_out;

  const int E = in_sizes[2];
  const int N = in_sizes[0] / (WW * CH);
  const int* srcA = A;
  const int* dstA = A + E;

  char* ws = (char*)d_ws;
  size_t off = 0;
  auto alloc = [&](size_t bytes) -> void* {
    void* p = ws + off;
    off += (bytes + 255) / 256 * 256;
    return p;
  };
  unsigned long long* degcnt = (unsigned long long*)alloc((size_t)N * 8);
  int*   rowptr = (int*)alloc((size_t)(N + 1) * 4);
  int*   wptr   = (int*)alloc((size_t)N * 4);
  int*   bsum   = (int*)alloc((size_t)SBT * 4);
  int2*  epair  = (int2*)alloc((size_t)E * 8);
  unsigned short* xt   = (unsigned short*)alloc((size_t)N * ROWB * 2);
  unsigned char*  xq   = (unsigned char*)alloc((size_t)N * ROWB);
  unsigned short* zt   = (unsigned short*)alloc((size_t)N * ROWB * 2);
  unsigned short* wb01 = (unsigned short*)alloc((size_t)24576 * 2);
  unsigned short* wbc  = (unsigned short*)alloc((size_t)3072 * 2);
  (void)ws_size;

  hipMemsetAsync(degcnt, 0, (size_t)N * 8, stream);

  degcnt_kernel<<<(E + 255) / 256, 256, 0, stream>>>(dstA, Ew, degcnt, E);

  const int nb = (N + SBT - 1) / SBT;   // 196 <= 256 for N=50000
  scanA_kernel<<<nb, SBT, 0, stream>>>(degcnt, bsum, N);
  scanB_kernel<<<1, SBT, 0, stream>>>(bsum, rowptr, nb, N);
  scanC_kernel<<<nb, SBT, 0, stream>>>(degcnt, bsum, rowptr, wptr, N);

  fill_kernel<<<(E + 255) / 256, 256, 0, stream>>>(srcA, dstA, Ew, degcnt, wptr, epair, E);

  dim3 gpack((N * CH + 255) / 256, WW);
  pack_kernel<<<gpack, 256, 0, stream>>>(x, Wcheb, Wconv, xt, xq, wb01, wbc, N);

  long long gtot = (long long)N * 64;
  gather_kernel<<<(unsigned)((gtot + 255) / 256), 256, 0, stream>>>(rowptr, epair, xq, zt, N);

  int ntiles = (N + 15) / 16;            // 16-node wave tiles
  int mcblocks = (ntiles + 3) / 4;       // 4 waves per block
  mc_kernel<<<mcblocks, 256, 0, stream>>>(xt, zt, wb01, wbc, bcheb, bconv, out, N);
}